// Round 1
// 182.482 us; speedup vs baseline: 1.0336x; 1.0336x over previous
//
#include <hip/hip_runtime.h>
#include <math.h>

// DiffKS round 4.
// Kernel A (parallel): unchanged — per-sample sparse-LPC coefficients v[0..6]
//   + band base into ws; exc-LPC coeffs interleaved [t*5+k].
// Kernel B (1 wave): phase-2 resonator restructured.
//   Round-3 ran 900 bodies of 49 samples at ~349 cy/body (mostly fixed
//   per-body stall). Round-4: C=100 (50 lanes x 2 samples), 441 bodies,
//   1-ahead history prefetch (dep distance >= 101 > 100), branchless LDS
//   (cndmask dump-slot addresses instead of branches), CF register ring of
//   4 bodies (prefetch distance 4), hu ping-pong on body parity with 4-body
//   static unroll.

#define T_SAMPLES 44100
#define NFRAMES   100
#define NCOEF     6
#define NACT      7
#define BURST     2048
#define EXC_ORD   5

#define C2        100           // samples per body
#define NB2       441           // 441*100 = 44100
#define HISTSZ    1096          // 1024 ring + 7 mirror + 1 + 64 dump slots

#define WS_COEF_FLOATS (T_SAMPLES * 8)
#define WS_EXC_OFF     WS_COEF_FLOATS
#define WS_EXC_FLOATS  (EXC_ORD * BURST)
#define WS_TOTAL_BYTES ((size_t)(WS_COEF_FLOATS + WS_EXC_FLOATS) * 4)

// ---------------------------------------------------------------- kernel A
__global__ __launch_bounds__(256) void diffks_precompute(
    const float* __restrict__ delay_frames,
    const float* __restrict__ raw_coeff,
    const float* __restrict__ raw_gain,
    const float* __restrict__ exc_coeff,
    float* __restrict__ ws)
{
    int g = blockIdx.x * 256 + threadIdx.x;
    const float gain = 0.1f / (1.0f + expf(-raw_gain[0])) + 0.9f;

    if (g < T_SAMPLES) {
        const float stepT = 99.0f / (float)(T_SAMPLES - 1);
        float pos = (float)g * stepT;
        int i0 = (int)pos; if (i0 > NFRAMES - 2) i0 = NFRAMES - 2;
        float w = pos - (float)i0;

        float d0 = delay_frames[i0], d1 = delay_frames[i0 + 1];
        float delay = d0 + (d1 - d0) * w;
        int z = (int)delay;                  // delay >= 100 > 0
        float alfa = delay - (float)z;

        float b[NCOEF];
        {
            float c0v[NCOEF], c1v[NCOEF];
            float s0 = 0.f, s1 = 0.f;
            #pragma unroll
            for (int j = 0; j < NCOEF; ++j) {
                c0v[j] = 1.0f / (1.0f + expf(-raw_coeff[i0 * NCOEF + j]));
                c1v[j] = 1.0f / (1.0f + expf(-raw_coeff[(i0 + 1) * NCOEF + j]));
                s0 += c0v[j]; s1 += c1v[j];
            }
            float g0 = gain / s0, g1 = gain / s1;
            #pragma unroll
            for (int j = 0; j < NCOEF; ++j) {
                float x0 = c0v[j] * g0, x1 = c1v[j] * g1;
                b[j] = x0 + (x1 - x0) * w;
            }
        }
        float oma = 1.0f - alfa;
        float v0 = -oma * b[0];
        float v1 = -(alfa * b[0] + oma * b[1]);
        float v2 = -(alfa * b[1] + oma * b[2]);
        float v3 = -(alfa * b[2] + oma * b[3]);
        float v4 = -(alfa * b[3] + oma * b[4]);
        float v5 = -(alfa * b[4] + oma * b[5]);
        float v6 = -alfa * b[5];
        int base = g - z - 1;

        float4* o = (float4*)(ws + (size_t)g * 8);
        o[0] = make_float4(v0, v1, v2, v3);
        o[1] = make_float4(v4, v5, v6, __int_as_float(base));
    } else if (g < T_SAMPLES + BURST) {
        int te = g - T_SAMPLES;
        const float stepE = 99.0f / (float)(BURST - 1);
        float pos = (float)te * stepE;
        int i0 = (int)pos; if (i0 > NFRAMES - 2) i0 = NFRAMES - 2;
        float w = pos - (float)i0;
        float* o = ws + WS_EXC_OFF + te * EXC_ORD;     // interleaved [t*5+k]
        #pragma unroll
        for (int k = 0; k < EXC_ORD; ++k) {
            float a0 = exc_coeff[i0 * EXC_ORD + k];
            float a1 = exc_coeff[(i0 + 1) * EXC_ORD + k];
            o[k] = a0 + (a1 - a0) * w;
        }
    }
}

// ---------------------------------------------------------------- kernel B
__global__ __launch_bounds__(64, 1) void diffks_serial(
    const float* __restrict__ excitation,
    const float* __restrict__ ws,
    float* __restrict__ out)
{
    __shared__ float s_x[64][33];        // burst (padded rows)
    __shared__ float s_a[64][161];       // exc coefs [seg][(i%32)*5+k]
    __shared__ float s_hist[HISTSZ];     // 1024 ring + 7 mirror + 64 dump
    __shared__ float s_tail[64][32];
    __shared__ float s_bound[64][6];

    const int lane = threadIdx.x;

    // ---- stage ----
    for (int t = lane; t < BURST; t += 64)
        s_x[t >> 5][t & 31] = excitation[t];
    {   // exc coefs: lane handles t = lane + 64*i, 5 contiguous scalars each
        for (int i = 0; i < 32; ++i) {
            int t = lane + i * 64;
            const float* g = ws + WS_EXC_OFF + t * EXC_ORD;
            float* dst = &s_a[t >> 5][(t & 31) * 5];
            dst[0] = g[0]; dst[1] = g[1]; dst[2] = g[2];
            dst[3] = g[3]; dst[4] = g[4];
        }
    }
    for (int i = lane; i < HISTSZ; i += 64) s_hist[i] = 0.0f;
    __syncthreads();

    // ---- phase 1: excitation LPC via 64-segment state-space scan ----
    {
        float st[6][5];
        #pragma unroll
        for (int r = 0; r < 6; ++r)
            #pragma unroll
            for (int k = 0; k < 5; ++k) st[r][k] = 0.0f;
        #pragma unroll
        for (int r = 1; r <= 5; ++r) st[r][r - 1] = 1.0f;

        const float* ar = &s_a[lane][0];
        const float* xr = &s_x[lane][0];
        #pragma unroll 8
        for (int i = 0; i < 32; ++i) {
            float a0 = ar[i * 5 + 0], a1 = ar[i * 5 + 1], a2 = ar[i * 5 + 2];
            float a3 = ar[i * 5 + 3], a4 = ar[i * 5 + 4];
            float xv = xr[i];
            #pragma unroll
            for (int r = 0; r < 6; ++r) {
                float acc = (r == 0) ? xv : 0.0f;
                acc = fmaf(-a0, st[r][0], acc);
                acc = fmaf(-a1, st[r][1], acc);
                acc = fmaf(-a2, st[r][2], acc);
                acc = fmaf(-a3, st[r][3], acc);
                acc = fmaf(-a4, st[r][4], acc);
                st[r][4] = st[r][3]; st[r][3] = st[r][2];
                st[r][2] = st[r][1]; st[r][1] = st[r][0];
                st[r][0] = acc;
            }
        }
        #pragma unroll
        for (int r = 0; r < 6; ++r)
            #pragma unroll
            for (int k = 0; k < 5; ++k)
                s_tail[lane][r * 5 + k] = st[r][k];
    }
    __syncthreads();

    if (lane == 0) {   // chain 5-dim boundary states through 64 segments
        float Y[5] = {0.f, 0.f, 0.f, 0.f, 0.f};
        for (int l = 0; l < 64; ++l) {
            #pragma unroll
            for (int c = 0; c < 5; ++c) s_bound[l][c] = Y[c];
            float tl[30];
            #pragma unroll
            for (int j = 0; j < 30; ++j) tl[j] = s_tail[l][j];
            float ny[5];
            #pragma unroll
            for (int k = 0; k < 5; ++k) {
                float acc = tl[k];
                #pragma unroll
                for (int c = 1; c <= 5; ++c)
                    acc = fmaf(tl[c * 5 + k], Y[c - 1], acc);
                ny[k] = acc;
            }
            #pragma unroll
            for (int k = 0; k < 5; ++k) Y[k] = ny[k];
        }
    }
    __syncthreads();

    {   // re-run each segment with correct boundary state
        float b0 = s_bound[lane][0], b1 = s_bound[lane][1], b2 = s_bound[lane][2];
        float b3 = s_bound[lane][3], b4 = s_bound[lane][4];
        const float* ar = &s_a[lane][0];
        float* xr = &s_x[lane][0];
        #pragma unroll 8
        for (int i = 0; i < 32; ++i) {
            float a0 = ar[i * 5 + 0], a1 = ar[i * 5 + 1], a2 = ar[i * 5 + 2];
            float a3 = ar[i * 5 + 3], a4 = ar[i * 5 + 4];
            float acc = xr[i];
            acc = fmaf(-a0, b0, acc);
            acc = fmaf(-a1, b1, acc);
            acc = fmaf(-a2, b2, acc);
            acc = fmaf(-a3, b3, acc);
            acc = fmaf(-a4, b4, acc);
            b4 = b3; b3 = b2; b2 = b1; b1 = b0; b0 = acc;
            xr[i] = acc;
        }
    }
    __syncthreads();

    // ---- phase 2: barrier-free resonator, C=100, 2 samples/lane ----
    const float4* cw = (const float4*)ws;
    const bool lane_act = (lane < 50);
    const unsigned dumpA = 1032u + (unsigned)lane;   // per-lane dump slot

    // CF ring: 4 bodies deep. Slot j holds body's 4 float4s:
    // [0],[1] = sample A (t = cc*100+lane), [2],[3] = sample B (t+50).
    float4 CFq[4][4];
    #pragma unroll
    for (int j = 0; j < 4; ++j) {
        int tA = j * C2 + lane;
        int tB = tA + 50;
        CFq[j][0] = cw[tA * 2 + 0];
        CFq[j][1] = cw[tA * 2 + 1];
        CFq[j][2] = cw[tB * 2 + 0];
        CFq[j][3] = cw[tB * 2 + 1];
    }

    // hu[parity][sample][k]: history y[base-6+k]; body 0's history is all
    // zeros (base < 0 for every sample of body 0 since z >= 100).
    float hu[2][2][7];
    #pragma unroll
    for (int k = 0; k < 7; ++k) {
        hu[0][0][k] = 0.f; hu[0][1][k] = 0.f;
        hu[1][0][k] = 0.f; hu[1][1][k] = 0.f;
    }

    // Body cc (slot j = cc&3, parity h = cc&1 = j&1):
    //  1. 14 FMAs (two independent 7-chains) using CFq[j], hu[h]
    //  2. branchless LDS writes (ring + mirror, inactive lanes -> dump)
    //  3. predicated global stores
    //  4. read history for body cc+1 (bases live in CFq[(j+1)&3]) -> hu[h^1]
    //  5. reload CFq[j] with body cc+4 (prefetch distance 4 bodies)
    #define KS2_BODY(cc, j, WITHX, DO_NEXT)                                    \
    {                                                                          \
        const float4 a0 = CFq[j][0], a1 = CFq[j][1];                           \
        const float4 b0 = CFq[j][2], b1 = CFq[j][3];                           \
        const int tA = (cc) * C2 + lane;                                       \
        const int tB = tA + 50;                                                \
        float accA, accB;                                                      \
        if (WITHX) {                                                           \
            accA = (lane_act && tA < BURST) ? s_x[tA >> 5][tA & 31] : 0.0f;    \
            accB = (lane_act && tB < BURST) ? s_x[tB >> 5][tB & 31] : 0.0f;    \
        } else { accA = 0.0f; accB = 0.0f; }                                   \
        accA = fmaf(-a0.x, hu[(j) & 1][0][6], accA);                           \
        accB = fmaf(-b0.x, hu[(j) & 1][1][6], accB);                           \
        accA = fmaf(-a0.y, hu[(j) & 1][0][5], accA);                           \
        accB = fmaf(-b0.y, hu[(j) & 1][1][5], accB);                           \
        accA = fmaf(-a0.z, hu[(j) & 1][0][4], accA);                           \
        accB = fmaf(-b0.z, hu[(j) & 1][1][4], accB);                           \
        accA = fmaf(-a0.w, hu[(j) & 1][0][3], accA);                           \
        accB = fmaf(-b0.w, hu[(j) & 1][1][3], accB);                           \
        accA = fmaf(-a1.x, hu[(j) & 1][0][2], accA);                           \
        accB = fmaf(-b1.x, hu[(j) & 1][1][2], accB);                           \
        accA = fmaf(-a1.y, hu[(j) & 1][0][1], accA);                           \
        accB = fmaf(-b1.y, hu[(j) & 1][1][1], accB);                           \
        accA = fmaf(-a1.z, hu[(j) & 1][0][0], accA);                           \
        accB = fmaf(-b1.z, hu[(j) & 1][1][0], accB);                           \
        const unsigned pA = ((unsigned)tA) & 1023u;                            \
        const unsigned pB = ((unsigned)tB) & 1023u;                            \
        s_hist[lane_act ? pA : dumpA] = accA;                                  \
        s_hist[lane_act ? pB : dumpA] = accB;                                  \
        s_hist[(lane_act && pA < 7u) ? (pA + 1024u) : dumpA] = accA;           \
        s_hist[(lane_act && pB < 7u) ? (pB + 1024u) : dumpA] = accB;           \
        if (lane_act) { out[tA] = accA; out[tB] = accB; }                      \
        if (DO_NEXT) {                                                         \
            int nbA = __float_as_int(CFq[((j) + 1) & 3][1].w);                 \
            int nbB = __float_as_int(CFq[((j) + 1) & 3][3].w);                 \
            unsigned qA = ((unsigned)(nbA - 6)) & 1023u;                       \
            unsigned qB = ((unsigned)(nbB - 6)) & 1023u;                       \
            hu[((j) & 1) ^ 1][0][0] = s_hist[qA + 0];                          \
            hu[((j) & 1) ^ 1][0][1] = s_hist[qA + 1];                          \
            hu[((j) & 1) ^ 1][0][2] = s_hist[qA + 2];                          \
            hu[((j) & 1) ^ 1][0][3] = s_hist[qA + 3];                          \
            hu[((j) & 1) ^ 1][0][4] = s_hist[qA + 4];                          \
            hu[((j) & 1) ^ 1][0][5] = s_hist[qA + 5];                          \
            hu[((j) & 1) ^ 1][0][6] = s_hist[qA + 6];                          \
            hu[((j) & 1) ^ 1][1][0] = s_hist[qB + 0];                          \
            hu[((j) & 1) ^ 1][1][1] = s_hist[qB + 1];                          \
            hu[((j) & 1) ^ 1][1][2] = s_hist[qB + 2];                          \
            hu[((j) & 1) ^ 1][1][3] = s_hist[qB + 3];                          \
            hu[((j) & 1) ^ 1][1][4] = s_hist[qB + 4];                          \
            hu[((j) & 1) ^ 1][1][5] = s_hist[qB + 5];                          \
            hu[((j) & 1) ^ 1][1][6] = s_hist[qB + 6];                          \
            int tA4 = ((cc) + 4) * C2 + lane;                                  \
            if (tA4 > T_SAMPLES - 1) tA4 = T_SAMPLES - 1;                      \
            int tB4 = tA4 + 50;                                                \
            if (tB4 > T_SAMPLES - 1) tB4 = T_SAMPLES - 1;                      \
            CFq[j][0] = cw[tA4 * 2 + 0];                                       \
            CFq[j][1] = cw[tA4 * 2 + 1];                                       \
            CFq[j][2] = cw[tB4 * 2 + 0];                                       \
            CFq[j][3] = cw[tB4 * 2 + 1];                                       \
        }                                                                      \
    }

    // bodies 0..23: excitation mix possible (covers all t < 2048, body 20)
    #pragma unroll 1
    for (int gb = 0; gb < 24; gb += 4) {
        KS2_BODY(gb + 0, 0, true, true)
        KS2_BODY(gb + 1, 1, true, true)
        KS2_BODY(gb + 2, 2, true, true)
        KS2_BODY(gb + 3, 3, true, true)
    }
    // bodies 24..439: steady state
    #pragma unroll 1
    for (int gb = 24; gb < 440; gb += 4) {
        KS2_BODY(gb + 0, 0, false, true)
        KS2_BODY(gb + 1, 1, false, true)
        KS2_BODY(gb + 2, 2, false, true)
        KS2_BODY(gb + 3, 3, false, true)
    }
    // tail body 440 (slot 0, parity 0; hu loaded by body 439, CFq[0] by 436)
    KS2_BODY(440, 0, false, false)
    #undef KS2_BODY
}

// ------------------------------------------------- fallback (round-1 kernel)
#define CHUNK_FB  101
#define NCH_FB    ((T_SAMPLES + CHUNK_FB - 1) / CHUNK_FB)
#define HIST_FB   1024

__global__ __launch_bounds__(128) void diffks_fallback(
    const float* __restrict__ delay_frames,
    const float* __restrict__ excitation,
    const float* __restrict__ raw_coeff,
    const float* __restrict__ raw_gain,
    const float* __restrict__ exc_coeff,
    float* __restrict__ out)
{
    __shared__ float s_a[EXC_ORD][BURST];
    __shared__ float s_x[BURST];
    __shared__ float s_hist[HIST_FB];
    __shared__ __align__(16) float s_coef[NFRAMES][8];
    __shared__ float s_delay[NFRAMES];

    const int tid = threadIdx.x;
    const float gain = 0.1f / (1.0f + expf(-raw_gain[0])) + 0.9f;

    for (int i = tid; i < NFRAMES; i += 128) s_delay[i] = delay_frames[i];
    for (int f = tid; f < NFRAMES; f += 128) {
        float sb[NCOEF]; float s = 0.0f;
        #pragma unroll
        for (int j = 0; j < NCOEF; ++j) {
            sb[j] = 1.0f / (1.0f + expf(-raw_coeff[f * NCOEF + j]));
            s += sb[j];
        }
        float inv = gain / s;
        #pragma unroll
        for (int j = 0; j < NCOEF; ++j) s_coef[f][j] = sb[j] * inv;
        s_coef[f][6] = 0.0f; s_coef[f][7] = 0.0f;
    }
    const float stepE = 99.0f / 2047.0f;
    for (int t = tid; t < BURST; t += 128) {
        float pos = (float)t * stepE;
        int i0 = (int)pos; if (i0 > NFRAMES - 2) i0 = NFRAMES - 2;
        float w = pos - (float)i0;
        const float* c0 = exc_coeff + i0 * EXC_ORD;
        #pragma unroll
        for (int k = 0; k < EXC_ORD; ++k) {
            float a0 = c0[k], a1 = c0[k + EXC_ORD];
            s_a[k][t] = a0 + (a1 - a0) * w;
        }
        s_x[t] = excitation[t];
    }
    for (int i = tid; i < HIST_FB; i += 128) s_hist[i] = 0.0f;
    __syncthreads();

    if (tid == 0) {
        float y1 = 0.f, y2 = 0.f, y3 = 0.f, y4 = 0.f, y5 = 0.f;
        #pragma unroll 4
        for (int t = 0; t < BURST; ++t) {
            float p = s_x[t];
            p = fmaf(-s_a[1][t], y2, p);
            p = fmaf(-s_a[2][t], y3, p);
            p = fmaf(-s_a[3][t], y4, p);
            p = fmaf(-s_a[4][t], y5, p);
            float y = fmaf(-s_a[0][t], y1, p);
            s_x[t] = y;
            y5 = y4; y4 = y3; y3 = y2; y2 = y1; y1 = y;
        }
    }
    __syncthreads();

    const float stepT = 99.0f / (float)(T_SAMPLES - 1);
    for (int c = 0; c < NCH_FB; ++c) {
        int t = c * CHUNK_FB + tid;
        if (tid < CHUNK_FB && t < T_SAMPLES) {
            float pos = (float)t * stepT;
            int i0 = (int)pos; if (i0 > NFRAMES - 2) i0 = NFRAMES - 2;
            float w = pos - (float)i0;
            float d0 = s_delay[i0], d1 = s_delay[i0 + 1];
            float delay = d0 + (d1 - d0) * w;
            int z = (int)delay;
            float alfa = delay - (float)z;
            const float4* f0 = reinterpret_cast<const float4*>(s_coef[i0]);
            const float4* f1 = reinterpret_cast<const float4*>(s_coef[i0 + 1]);
            float4 c0a = f0[0], c0b = f0[1];
            float4 c1a = f1[0], c1b = f1[1];
            float b[NCOEF];
            b[0] = c0a.x + (c1a.x - c0a.x) * w;
            b[1] = c0a.y + (c1a.y - c0a.y) * w;
            b[2] = c0a.z + (c1a.z - c0a.z) * w;
            b[3] = c0a.w + (c1a.w - c0a.w) * w;
            b[4] = c0b.x + (c1b.x - c0b.x) * w;
            b[5] = c0b.y + (c1b.y - c0b.y) * w;
            float oma = 1.0f - alfa;
            float v[NACT];
            v[0] = -oma * b[0];
            #pragma unroll
            for (int j = 1; j <= 5; ++j) v[j] = -(alfa * b[j - 1] + oma * b[j]);
            v[6] = -alfa * b[5];
            float x = (t < BURST) ? s_x[t] : 0.0f;
            int base = t - z - 1;
            float sum = 0.0f;
            #pragma unroll
            for (int j = 0; j < NACT; ++j) {
                int idx = base - j;
                float yv = s_hist[idx & (HIST_FB - 1)];
                if (idx < 0) yv = 0.0f;
                sum = fmaf(v[j], yv, sum);
            }
            float y = x - sum;
            s_hist[t & (HIST_FB - 1)] = y;
            out[t] = y;
        }
        __syncthreads();
    }
}

// ---------------------------------------------------------------- launch
extern "C" void kernel_launch(void* const* d_in, const int* in_sizes, int n_in,
                              void* d_out, int out_size, void* d_ws, size_t ws_size,
                              hipStream_t stream) {
    const float* delay_frames = (const float*)d_in[0];
    const float* excitation   = (const float*)d_in[1];
    const float* raw_coeff    = (const float*)d_in[2];
    const float* raw_gain     = (const float*)d_in[3];
    const float* exc_coeff    = (const float*)d_in[4];
    float* out = (float*)d_out;

    if (ws_size >= WS_TOTAL_BYTES) {
        float* ws = (float*)d_ws;
        int gridA = (T_SAMPLES + BURST + 255) / 256;
        diffks_precompute<<<gridA, 256, 0, stream>>>(delay_frames, raw_coeff,
                                                     raw_gain, exc_coeff, ws);
        diffks_serial<<<1, 64, 0, stream>>>(excitation, ws, out);
    } else {
        diffks_fallback<<<1, 128, 0, stream>>>(delay_frames, excitation,
                                               raw_coeff, raw_gain, exc_coeff, out);
    }
}

// Round 2
// 174.367 us; speedup vs baseline: 1.0817x; 1.0465x over previous
//
#include <hip/hip_runtime.h>
#include <math.h>

// DiffKS round 5.
// Kernel A (parallel): unchanged.
// Kernel B (1 wave), phase 2 changes vs round 4:
//   * NO per-body global stores: output dumped from the s_hist ring every
//     8 bodies (800 samples, coalesced). Removes the per-body vmcnt WAR
//     drain on acc registers (suspected ~300-400 cy/body stall).
//   * CF register ring deepened 4 -> 8 bodies so the .w (base) field is
//     consumed ~1500 cy after its global load (covers L3 latency).
//   * Body is fully branchless; only VMEM in the loop = 4 CF loads/body.
//   FMA order per sample is bit-identical to round 4 (absmax at threshold).

#define T_SAMPLES 44100
#define NFRAMES   100
#define NCOEF     6
#define NACT      7
#define BURST     2048
#define EXC_ORD   5

#define C2        100           // samples per body
#define HISTSZ    1096          // 1024 ring + 7 mirror + 1 + 64 dump slots

#define WS_COEF_FLOATS (T_SAMPLES * 8)
#define WS_EXC_OFF     WS_COEF_FLOATS
#define WS_EXC_FLOATS  (EXC_ORD * BURST)
#define WS_TOTAL_BYTES ((size_t)(WS_COEF_FLOATS + WS_EXC_FLOATS) * 4)

// ---------------------------------------------------------------- kernel A
__global__ __launch_bounds__(256) void diffks_precompute(
    const float* __restrict__ delay_frames,
    const float* __restrict__ raw_coeff,
    const float* __restrict__ raw_gain,
    const float* __restrict__ exc_coeff,
    float* __restrict__ ws)
{
    int g = blockIdx.x * 256 + threadIdx.x;
    const float gain = 0.1f / (1.0f + expf(-raw_gain[0])) + 0.9f;

    if (g < T_SAMPLES) {
        const float stepT = 99.0f / (float)(T_SAMPLES - 1);
        float pos = (float)g * stepT;
        int i0 = (int)pos; if (i0 > NFRAMES - 2) i0 = NFRAMES - 2;
        float w = pos - (float)i0;

        float d0 = delay_frames[i0], d1 = delay_frames[i0 + 1];
        float delay = d0 + (d1 - d0) * w;
        int z = (int)delay;                  // delay >= 100 > 0
        float alfa = delay - (float)z;

        float b[NCOEF];
        {
            float c0v[NCOEF], c1v[NCOEF];
            float s0 = 0.f, s1 = 0.f;
            #pragma unroll
            for (int j = 0; j < NCOEF; ++j) {
                c0v[j] = 1.0f / (1.0f + expf(-raw_coeff[i0 * NCOEF + j]));
                c1v[j] = 1.0f / (1.0f + expf(-raw_coeff[(i0 + 1) * NCOEF + j]));
                s0 += c0v[j]; s1 += c1v[j];
            }
            float g0 = gain / s0, g1 = gain / s1;
            #pragma unroll
            for (int j = 0; j < NCOEF; ++j) {
                float x0 = c0v[j] * g0, x1 = c1v[j] * g1;
                b[j] = x0 + (x1 - x0) * w;
            }
        }
        float oma = 1.0f - alfa;
        float v0 = -oma * b[0];
        float v1 = -(alfa * b[0] + oma * b[1]);
        float v2 = -(alfa * b[1] + oma * b[2]);
        float v3 = -(alfa * b[2] + oma * b[3]);
        float v4 = -(alfa * b[3] + oma * b[4]);
        float v5 = -(alfa * b[4] + oma * b[5]);
        float v6 = -alfa * b[5];
        int base = g - z - 1;

        float4* o = (float4*)(ws + (size_t)g * 8);
        o[0] = make_float4(v0, v1, v2, v3);
        o[1] = make_float4(v4, v5, v6, __int_as_float(base));
    } else if (g < T_SAMPLES + BURST) {
        int te = g - T_SAMPLES;
        const float stepE = 99.0f / (float)(BURST - 1);
        float pos = (float)te * stepE;
        int i0 = (int)pos; if (i0 > NFRAMES - 2) i0 = NFRAMES - 2;
        float w = pos - (float)i0;
        float* o = ws + WS_EXC_OFF + te * EXC_ORD;     // interleaved [t*5+k]
        #pragma unroll
        for (int k = 0; k < EXC_ORD; ++k) {
            float a0 = exc_coeff[i0 * EXC_ORD + k];
            float a1 = exc_coeff[(i0 + 1) * EXC_ORD + k];
            o[k] = a0 + (a1 - a0) * w;
        }
    }
}

// ---------------------------------------------------------------- kernel B
__global__ __launch_bounds__(64, 1) void diffks_serial(
    const float* __restrict__ excitation,
    const float* __restrict__ ws,
    float* __restrict__ out)
{
    __shared__ float s_x[64][33];        // burst (padded rows)
    __shared__ float s_a[64][161];       // exc coefs [seg][(i%32)*5+k]
    __shared__ float s_hist[HISTSZ];     // 1024 ring + 7 mirror + 64 dump
    __shared__ float s_tail[64][32];
    __shared__ float s_bound[64][6];

    const int lane = threadIdx.x;

    // ---- stage ----
    for (int t = lane; t < BURST; t += 64)
        s_x[t >> 5][t & 31] = excitation[t];
    {   // exc coefs: lane handles t = lane + 64*i, 5 contiguous scalars each
        for (int i = 0; i < 32; ++i) {
            int t = lane + i * 64;
            const float* g = ws + WS_EXC_OFF + t * EXC_ORD;
            float* dst = &s_a[t >> 5][(t & 31) * 5];
            dst[0] = g[0]; dst[1] = g[1]; dst[2] = g[2];
            dst[3] = g[3]; dst[4] = g[4];
        }
    }
    for (int i = lane; i < HISTSZ; i += 64) s_hist[i] = 0.0f;
    __syncthreads();

    // ---- phase 1: excitation LPC via 64-segment state-space scan ----
    {
        float st[6][5];
        #pragma unroll
        for (int r = 0; r < 6; ++r)
            #pragma unroll
            for (int k = 0; k < 5; ++k) st[r][k] = 0.0f;
        #pragma unroll
        for (int r = 1; r <= 5; ++r) st[r][r - 1] = 1.0f;

        const float* ar = &s_a[lane][0];
        const float* xr = &s_x[lane][0];
        #pragma unroll 8
        for (int i = 0; i < 32; ++i) {
            float a0 = ar[i * 5 + 0], a1 = ar[i * 5 + 1], a2 = ar[i * 5 + 2];
            float a3 = ar[i * 5 + 3], a4 = ar[i * 5 + 4];
            float xv = xr[i];
            #pragma unroll
            for (int r = 0; r < 6; ++r) {
                float acc = (r == 0) ? xv : 0.0f;
                acc = fmaf(-a0, st[r][0], acc);
                acc = fmaf(-a1, st[r][1], acc);
                acc = fmaf(-a2, st[r][2], acc);
                acc = fmaf(-a3, st[r][3], acc);
                acc = fmaf(-a4, st[r][4], acc);
                st[r][4] = st[r][3]; st[r][3] = st[r][2];
                st[r][2] = st[r][1]; st[r][1] = st[r][0];
                st[r][0] = acc;
            }
        }
        #pragma unroll
        for (int r = 0; r < 6; ++r)
            #pragma unroll
            for (int k = 0; k < 5; ++k)
                s_tail[lane][r * 5 + k] = st[r][k];
    }
    __syncthreads();

    if (lane == 0) {   // chain 5-dim boundary states through 64 segments
        float Y[5] = {0.f, 0.f, 0.f, 0.f, 0.f};
        for (int l = 0; l < 64; ++l) {
            #pragma unroll
            for (int c = 0; c < 5; ++c) s_bound[l][c] = Y[c];
            float tl[30];
            #pragma unroll
            for (int j = 0; j < 30; ++j) tl[j] = s_tail[l][j];
            float ny[5];
            #pragma unroll
            for (int k = 0; k < 5; ++k) {
                float acc = tl[k];
                #pragma unroll
                for (int c = 1; c <= 5; ++c)
                    acc = fmaf(tl[c * 5 + k], Y[c - 1], acc);
                ny[k] = acc;
            }
            #pragma unroll
            for (int k = 0; k < 5; ++k) Y[k] = ny[k];
        }
    }
    __syncthreads();

    {   // re-run each segment with correct boundary state
        float b0 = s_bound[lane][0], b1 = s_bound[lane][1], b2 = s_bound[lane][2];
        float b3 = s_bound[lane][3], b4 = s_bound[lane][4];
        const float* ar = &s_a[lane][0];
        float* xr = &s_x[lane][0];
        #pragma unroll 8
        for (int i = 0; i < 32; ++i) {
            float a0 = ar[i * 5 + 0], a1 = ar[i * 5 + 1], a2 = ar[i * 5 + 2];
            float a3 = ar[i * 5 + 3], a4 = ar[i * 5 + 4];
            float acc = xr[i];
            acc = fmaf(-a0, b0, acc);
            acc = fmaf(-a1, b1, acc);
            acc = fmaf(-a2, b2, acc);
            acc = fmaf(-a3, b3, acc);
            acc = fmaf(-a4, b4, acc);
            b4 = b3; b3 = b2; b2 = b1; b1 = b0; b0 = acc;
            xr[i] = acc;
        }
    }
    __syncthreads();

    // ---- phase 2: barrier-free resonator, C=100, 2 samples/lane ----
    const float4* cw = (const float4*)ws;
    const bool lane_act = (lane < 50);
    const unsigned dumpA = 1032u + (unsigned)lane;   // per-lane dump slot

    // CF ring: 8 bodies deep. Slot j holds body's 4 float4s:
    // [0],[1] = sample A (t = cc*100+lane), [2],[3] = sample B (t+50).
    float4 CFq[8][4];
    #pragma unroll
    for (int j = 0; j < 8; ++j) {
        int tA = j * C2 + lane;
        int tB = tA + 50;
        CFq[j][0] = cw[tA * 2 + 0];
        CFq[j][1] = cw[tA * 2 + 1];
        CFq[j][2] = cw[tB * 2 + 0];
        CFq[j][3] = cw[tB * 2 + 1];
    }

    // hu[parity][sample][k]: history y[base-6+k]; body 0's history is all
    // zeros (base < 0 for every sample of body 0 since z >= 100).
    float hu[2][2][7];
    #pragma unroll
    for (int k = 0; k < 7; ++k) {
        hu[0][0][k] = 0.f; hu[0][1][k] = 0.f;
        hu[1][0][k] = 0.f; hu[1][1][k] = 0.f;
    }

    // Body cc (slot j = cc&7, parity h = cc&1 = j&1):
    //  1. 14 FMAs (two independent 7-chains) using CFq[j], hu[h]
    //  2. branchless LDS writes (ring + mirror, inactive lanes -> dump)
    //  3. read history for body cc+1 (bases live in CFq[(j+1)&7]) -> hu[h^1]
    //  4. reload CFq[j] with body cc+8 (prefetch distance 8 bodies)
    // NO global stores here — output is dumped from the ring per group.
    #define KS2_BODY(cc, j, WITHX, DO_NEXT)                                    \
    {                                                                          \
        const float4 a0 = CFq[j][0], a1 = CFq[j][1];                           \
        const float4 b0 = CFq[j][2], b1 = CFq[j][3];                           \
        const int tA = (cc) * C2 + lane;                                       \
        const int tB = tA + 50;                                                \
        float accA, accB;                                                      \
        if (WITHX) {                                                           \
            accA = (lane_act && tA < BURST) ? s_x[tA >> 5][tA & 31] : 0.0f;    \
            accB = (lane_act && tB < BURST) ? s_x[tB >> 5][tB & 31] : 0.0f;    \
        } else { accA = 0.0f; accB = 0.0f; }                                   \
        accA = fmaf(-a0.x, hu[(j) & 1][0][6], accA);                           \
        accB = fmaf(-b0.x, hu[(j) & 1][1][6], accB);                           \
        accA = fmaf(-a0.y, hu[(j) & 1][0][5], accA);                           \
        accB = fmaf(-b0.y, hu[(j) & 1][1][5], accB);                           \
        accA = fmaf(-a0.z, hu[(j) & 1][0][4], accA);                           \
        accB = fmaf(-b0.z, hu[(j) & 1][1][4], accB);                           \
        accA = fmaf(-a0.w, hu[(j) & 1][0][3], accA);                           \
        accB = fmaf(-b0.w, hu[(j) & 1][1][3], accB);                           \
        accA = fmaf(-a1.x, hu[(j) & 1][0][2], accA);                           \
        accB = fmaf(-b1.x, hu[(j) & 1][1][2], accB);                           \
        accA = fmaf(-a1.y, hu[(j) & 1][0][1], accA);                           \
        accB = fmaf(-b1.y, hu[(j) & 1][1][1], accB);                           \
        accA = fmaf(-a1.z, hu[(j) & 1][0][0], accA);                           \
        accB = fmaf(-b1.z, hu[(j) & 1][1][0], accB);                           \
        const unsigned pA = ((unsigned)tA) & 1023u;                            \
        const unsigned pB = ((unsigned)tB) & 1023u;                            \
        s_hist[lane_act ? pA : dumpA] = accA;                                  \
        s_hist[lane_act ? pB : dumpA] = accB;                                  \
        s_hist[(lane_act && pA < 7u) ? (pA + 1024u) : dumpA] = accA;           \
        s_hist[(lane_act && pB < 7u) ? (pB + 1024u) : dumpA] = accB;           \
        if (DO_NEXT) {                                                         \
            int nbA = __float_as_int(CFq[((j) + 1) & 7][1].w);                 \
            int nbB = __float_as_int(CFq[((j) + 1) & 7][3].w);                 \
            unsigned qA = ((unsigned)(nbA - 6)) & 1023u;                       \
            unsigned qB = ((unsigned)(nbB - 6)) & 1023u;                       \
            hu[((j) & 1) ^ 1][0][0] = s_hist[qA + 0];                          \
            hu[((j) & 1) ^ 1][0][1] = s_hist[qA + 1];                          \
            hu[((j) & 1) ^ 1][0][2] = s_hist[qA + 2];                          \
            hu[((j) & 1) ^ 1][0][3] = s_hist[qA + 3];                          \
            hu[((j) & 1) ^ 1][0][4] = s_hist[qA + 4];                          \
            hu[((j) & 1) ^ 1][0][5] = s_hist[qA + 5];                          \
            hu[((j) & 1) ^ 1][0][6] = s_hist[qA + 6];                          \
            hu[((j) & 1) ^ 1][1][0] = s_hist[qB + 0];                          \
            hu[((j) & 1) ^ 1][1][1] = s_hist[qB + 1];                          \
            hu[((j) & 1) ^ 1][1][2] = s_hist[qB + 2];                          \
            hu[((j) & 1) ^ 1][1][3] = s_hist[qB + 3];                          \
            hu[((j) & 1) ^ 1][1][4] = s_hist[qB + 4];                          \
            hu[((j) & 1) ^ 1][1][5] = s_hist[qB + 5];                          \
            hu[((j) & 1) ^ 1][1][6] = s_hist[qB + 6];                          \
            int tA8 = ((cc) + 8) * C2 + lane;                                  \
            if (tA8 > T_SAMPLES - 1) tA8 = T_SAMPLES - 1;                      \
            int tB8 = tA8 + 50;                                                \
            if (tB8 > T_SAMPLES - 1) tB8 = T_SAMPLES - 1;                      \
            CFq[j][0] = cw[tA8 * 2 + 0];                                       \
            CFq[j][1] = cw[tA8 * 2 + 1];                                       \
            CFq[j][2] = cw[tB8 * 2 + 0];                                       \
            CFq[j][3] = cw[tB8 * 2 + 1];                                       \
        }                                                                      \
    }

    // dump 800 samples of group g from the ring (coalesced, off-chain)
    #define DUMP800(g)                                                         \
    {                                                                          \
        const int t0 = (g) * 800;                                              \
        _Pragma("unroll")                                                      \
        for (int i = 0; i < 12; ++i) {                                         \
            int t = t0 + i * 64 + lane;                                        \
            out[t] = s_hist[((unsigned)t) & 1023u];                            \
        }                                                                      \
        {                                                                      \
            int t = t0 + 768 + lane;                                           \
            if (lane < 32) out[t] = s_hist[((unsigned)t) & 1023u];             \
        }                                                                      \
    }

    // groups 0..2 (bodies 0..23): excitation mix active (t < 2400 covers 2048)
    #pragma unroll 1
    for (int g = 0; g < 3; ++g) {
        const int cb = g * 8;
        KS2_BODY(cb + 0, 0, true, true)
        KS2_BODY(cb + 1, 1, true, true)
        KS2_BODY(cb + 2, 2, true, true)
        KS2_BODY(cb + 3, 3, true, true)
        KS2_BODY(cb + 4, 4, true, true)
        KS2_BODY(cb + 5, 5, true, true)
        KS2_BODY(cb + 6, 6, true, true)
        KS2_BODY(cb + 7, 7, true, true)
        DUMP800(g)
    }
    // groups 3..54 (bodies 24..439): steady state
    #pragma unroll 1
    for (int g = 3; g < 55; ++g) {
        const int cb = g * 8;
        KS2_BODY(cb + 0, 0, false, true)
        KS2_BODY(cb + 1, 1, false, true)
        KS2_BODY(cb + 2, 2, false, true)
        KS2_BODY(cb + 3, 3, false, true)
        KS2_BODY(cb + 4, 4, false, true)
        KS2_BODY(cb + 5, 5, false, true)
        KS2_BODY(cb + 6, 6, false, true)
        KS2_BODY(cb + 7, 7, false, true)
        DUMP800(g)
    }
    // tail body 440 (slot 0, parity 0; hu loaded by body 439, CFq[0] by 432)
    KS2_BODY(440, 0, false, false)
    // final dump: t in [44000, 44100)
    {
        int t = 44000 + lane;
        out[t] = s_hist[((unsigned)t) & 1023u];
        int t2 = t + 64;
        if (lane < 36) out[t2] = s_hist[((unsigned)t2) & 1023u];
    }
    #undef KS2_BODY
    #undef DUMP800
}

// ------------------------------------------------- fallback (round-1 kernel)
#define CHUNK_FB  101
#define NCH_FB    ((T_SAMPLES + CHUNK_FB - 1) / CHUNK_FB)
#define HIST_FB   1024

__global__ __launch_bounds__(128) void diffks_fallback(
    const float* __restrict__ delay_frames,
    const float* __restrict__ excitation,
    const float* __restrict__ raw_coeff,
    const float* __restrict__ raw_gain,
    const float* __restrict__ exc_coeff,
    float* __restrict__ out)
{
    __shared__ float s_a[EXC_ORD][BURST];
    __shared__ float s_x[BURST];
    __shared__ float s_hist[HIST_FB];
    __shared__ __align__(16) float s_coef[NFRAMES][8];
    __shared__ float s_delay[NFRAMES];

    const int tid = threadIdx.x;
    const float gain = 0.1f / (1.0f + expf(-raw_gain[0])) + 0.9f;

    for (int i = tid; i < NFRAMES; i += 128) s_delay[i] = delay_frames[i];
    for (int f = tid; f < NFRAMES; f += 128) {
        float sb[NCOEF]; float s = 0.0f;
        #pragma unroll
        for (int j = 0; j < NCOEF; ++j) {
            sb[j] = 1.0f / (1.0f + expf(-raw_coeff[f * NCOEF + j]));
            s += sb[j];
        }
        float inv = gain / s;
        #pragma unroll
        for (int j = 0; j < NCOEF; ++j) s_coef[f][j] = sb[j] * inv;
        s_coef[f][6] = 0.0f; s_coef[f][7] = 0.0f;
    }
    const float stepE = 99.0f / 2047.0f;
    for (int t = tid; t < BURST; t += 128) {
        float pos = (float)t * stepE;
        int i0 = (int)pos; if (i0 > NFRAMES - 2) i0 = NFRAMES - 2;
        float w = pos - (float)i0;
        const float* c0 = exc_coeff + i0 * EXC_ORD;
        #pragma unroll
        for (int k = 0; k < EXC_ORD; ++k) {
            float a0 = c0[k], a1 = c0[k + EXC_ORD];
            s_a[k][t] = a0 + (a1 - a0) * w;
        }
        s_x[t] = excitation[t];
    }
    for (int i = tid; i < HIST_FB; i += 128) s_hist[i] = 0.0f;
    __syncthreads();

    if (tid == 0) {
        float y1 = 0.f, y2 = 0.f, y3 = 0.f, y4 = 0.f, y5 = 0.f;
        #pragma unroll 4
        for (int t = 0; t < BURST; ++t) {
            float p = s_x[t];
            p = fmaf(-s_a[1][t], y2, p);
            p = fmaf(-s_a[2][t], y3, p);
            p = fmaf(-s_a[3][t], y4, p);
            p = fmaf(-s_a[4][t], y5, p);
            float y = fmaf(-s_a[0][t], y1, p);
            s_x[t] = y;
            y5 = y4; y4 = y3; y3 = y2; y2 = y1; y1 = y;
        }
    }
    __syncthreads();

    const float stepT = 99.0f / (float)(T_SAMPLES - 1);
    for (int c = 0; c < NCH_FB; ++c) {
        int t = c * CHUNK_FB + tid;
        if (tid < CHUNK_FB && t < T_SAMPLES) {
            float pos = (float)t * stepT;
            int i0 = (int)pos; if (i0 > NFRAMES - 2) i0 = NFRAMES - 2;
            float w = pos - (float)i0;
            float d0 = s_delay[i0], d1 = s_delay[i0 + 1];
            float delay = d0 + (d1 - d0) * w;
            int z = (int)delay;
            float alfa = delay - (float)z;
            const float4* f0 = reinterpret_cast<const float4*>(s_coef[i0]);
            const float4* f1 = reinterpret_cast<const float4*>(s_coef[i0 + 1]);
            float4 c0a = f0[0], c0b = f0[1];
            float4 c1a = f1[0], c1b = f1[1];
            float b[NCOEF];
            b[0] = c0a.x + (c1a.x - c0a.x) * w;
            b[1] = c0a.y + (c1a.y - c0a.y) * w;
            b[2] = c0a.z + (c1a.z - c0a.z) * w;
            b[3] = c0a.w + (c1a.w - c0a.w) * w;
            b[4] = c0b.x + (c1b.x - c0b.x) * w;
            b[5] = c0b.y + (c1b.y - c0b.y) * w;
            float oma = 1.0f - alfa;
            float v[NACT];
            v[0] = -oma * b[0];
            #pragma unroll
            for (int j = 1; j <= 5; ++j) v[j] = -(alfa * b[j - 1] + oma * b[j]);
            v[6] = -alfa * b[5];
            float x = (t < BURST) ? s_x[t] : 0.0f;
            int base = t - z - 1;
            float sum = 0.0f;
            #pragma unroll
            for (int j = 0; j < NACT; ++j) {
                int idx = base - j;
                float yv = s_hist[idx & (HIST_FB - 1)];
                if (idx < 0) yv = 0.0f;
                sum = fmaf(v[j], yv, sum);
            }
            float y = x - sum;
            s_hist[t & (HIST_FB - 1)] = y;
            out[t] = y;
        }
        __syncthreads();
    }
}

// ---------------------------------------------------------------- launch
extern "C" void kernel_launch(void* const* d_in, const int* in_sizes, int n_in,
                              void* d_out, int out_size, void* d_ws, size_t ws_size,
                              hipStream_t stream) {
    const float* delay_frames = (const float*)d_in[0];
    const float* excitation   = (const float*)d_in[1];
    const float* raw_coeff    = (const float*)d_in[2];
    const float* raw_gain     = (const float*)d_in[3];
    const float* exc_coeff    = (const float*)d_in[4];
    float* out = (float*)d_out;

    if (ws_size >= WS_TOTAL_BYTES) {
        float* ws = (float*)d_ws;
        int gridA = (T_SAMPLES + BURST + 255) / 256;
        diffks_precompute<<<gridA, 256, 0, stream>>>(delay_frames, raw_coeff,
                                                     raw_gain, exc_coeff, ws);
        diffks_serial<<<1, 64, 0, stream>>>(excitation, ws, out);
    } else {
        diffks_fallback<<<1, 128, 0, stream>>>(delay_frames, excitation,
                                               raw_coeff, raw_gain, exc_coeff, out);
    }
}